// Round 1
// baseline (63007.025 us; speedup 1.0000x reference)
//
#include <hip/hip_runtime.h>

#define T_LEN 512
#define HID   64
#define NG    256   // 4*HID gate rows
#define B_TILE 4

typedef float f4 __attribute__((ext_vector_type(4)));

__device__ __forceinline__ float sigm(float x)  { return 1.0f / (1.0f + __expf(-x)); }
__device__ __forceinline__ float tanh_f(float x){ float e = __expf(2.0f * x); return 1.0f - 2.0f / (e + 1.0f); }

__global__ __launch_bounds__(256, 2)
void lstm2_kernel(const float* __restrict__ x,
                  const float* __restrict__ Wih0, const float* __restrict__ Whh0,
                  const float* __restrict__ bih0, const float* __restrict__ bhh0,
                  const float* __restrict__ Wih1, const float* __restrict__ Whh1,
                  const float* __restrict__ bih1, const float* __restrict__ bhh1,
                  const float* __restrict__ Wh1,  const float* __restrict__ bh1,
                  const float* __restrict__ Wh2,  const float* __restrict__ bh2,
                  float* __restrict__ out)
{
    // [h][b] layout: one ds_read_b128 broadcast serves all 4 batch lanes
    __shared__ __align__(16) float xs[T_LEN][4][B_TILE];   // 32 KB, [t][f][b]
    __shared__ __align__(16) float h1s[HID][B_TILE];       // 1 KB
    __shared__ __align__(16) float h2s[HID][B_TILE];       // 1 KB
    __shared__ __align__(16) float g0s[NG][B_TILE];        // 4 KB
    __shared__ __align__(16) float g1s[NG][B_TILE];        // 4 KB
    __shared__ __align__(16) float hds[32][B_TILE];

    const int tid = threadIdx.x;
    const int b0  = blockIdx.x * B_TILE;
    const int g   = tid;            // gate row owned by this thread
    const int j   = tid & 63;       // hidden channel for update phase
    const int bb  = tid >> 6;       // batch lane for update phase
    const int wv  = tid >> 6;       // wave id -> gate type (0:i 1:f 2:g 3:o)

    // ---- per-thread weights in registers (~200 VGPRs) ----
    f4 wih0r = *(const f4*)(Wih0 + g * 4);
    f4 whh0r[16], wih1r[16], whh1r[16];
    {
        const f4* p0 = (const f4*)(Whh0 + g * HID);
        const f4* p1 = (const f4*)(Wih1 + g * HID);
        const f4* p2 = (const f4*)(Whh1 + g * HID);
#pragma unroll
        for (int k = 0; k < 16; ++k) { whh0r[k] = p0[k]; wih1r[k] = p1[k]; whh1r[k] = p2[k]; }
    }
    const float bias0 = bih0[g] + bhh0[g];
    const float bias1 = bih1[g] + bhh1[g];

    // ---- stage x slice: x[b0+bb][t][f] -> xs[t][f][bb] ----
    {
        const f4* xg = (const f4*)(x + (size_t)b0 * T_LEN * 4);
        for (int i = tid; i < B_TILE * T_LEN; i += 256) {
            const int xb = i >> 9;          // /T_LEN
            const int t  = i & (T_LEN - 1);
            f4 v = xg[i];
#pragma unroll
            for (int f = 0; f < 4; ++f) xs[t][f][xb] = v[f];
        }
    }
    // zero h state (harness poisons LDS-backing with 0xAA conceptually; we must init)
    ((float*)h1s)[tid] = 0.0f;   // HID*B_TILE == 256 == blockDim
    ((float*)h2s)[tid] = 0.0f;
    float c1 = 0.0f, c2 = 0.0f;

    __syncthreads();

    const f4* h1v = (const f4*)h1s;   // h1v[h] = h1s[h][0..3]
    const f4* h2v = (const f4*)h2s;

    for (int t = 0; t < T_LEN; ++t) {
        // ---- layer 0 matvec: gates0[b][g] ----
        {
            f4 acc = {bias0, bias0, bias0, bias0};
#pragma unroll
            for (int f = 0; f < 4; ++f) {
                f4 xv = *(const f4*)&xs[t][f][0];
                acc += xv * wih0r[f];
            }
#pragma unroll
            for (int h = 0; h < HID; ++h)
                acc += h1v[h] * whh0r[h >> 2][h & 3];
            f4 av;
            if (wv == 2) {
#pragma unroll
                for (int i = 0; i < 4; ++i) av[i] = tanh_f(acc[i]);
            } else {
#pragma unroll
                for (int i = 0; i < 4; ++i) av[i] = sigm(acc[i]);
            }
            *(f4*)&g0s[g][0] = av;
        }
        __syncthreads();
        // ---- layer 0 elementwise update ----
        {
            float ig = g0s[j][bb], fg = g0s[64 + j][bb], gg = g0s[128 + j][bb], og = g0s[192 + j][bb];
            c1 = fg * c1 + ig * gg;
            h1s[j][bb] = og * tanh_f(c1);
        }
        __syncthreads();
        // ---- layer 1 matvec: gates1[b][g] (inputs h1_t and h2_{t-1}) ----
        {
            f4 acc = {bias1, bias1, bias1, bias1};
#pragma unroll
            for (int h = 0; h < HID; ++h)
                acc += h1v[h] * wih1r[h >> 2][h & 3];
#pragma unroll
            for (int h = 0; h < HID; ++h)
                acc += h2v[h] * whh1r[h >> 2][h & 3];
            f4 av;
            if (wv == 2) {
#pragma unroll
                for (int i = 0; i < 4; ++i) av[i] = tanh_f(acc[i]);
            } else {
#pragma unroll
                for (int i = 0; i < 4; ++i) av[i] = sigm(acc[i]);
            }
            *(f4*)&g1s[g][0] = av;
        }
        __syncthreads();
        // ---- layer 1 elementwise update (no barrier needed before next MV0:
        // MV0 touches only xs/h1s/g0s, all disjoint from h2s/g1s) ----
        {
            float ig = g1s[j][bb], fg = g1s[64 + j][bb], gg = g1s[128 + j][bb], og = g1s[192 + j][bb];
            c2 = fg * c2 + ig * gg;
            h2s[j][bb] = og * tanh_f(c2);
        }
    }
    __syncthreads();

    // ---- head: Linear(64,32) + ReLU + Linear(32,1) ----
    if (tid < 128) {
        const int k = tid & 31, b = tid >> 5;
        float a = bh1[k];
#pragma unroll 8
        for (int jj = 0; jj < HID; ++jj) a += Wh1[k * HID + jj] * h2s[jj][b];
        hds[k][b] = fmaxf(a, 0.0f);
    }
    __syncthreads();
    if (tid < B_TILE) {
        float a = bh2[0];
#pragma unroll
        for (int k = 0; k < 32; ++k) a += Wh2[k] * hds[k][tid];
        out[b0 + tid] = a;
    }
}

extern "C" void kernel_launch(void* const* d_in, const int* in_sizes, int n_in,
                              void* d_out, int out_size, void* d_ws, size_t ws_size,
                              hipStream_t stream) {
    const float* x    = (const float*)d_in[0];
    const float* Wih0 = (const float*)d_in[1];
    const float* Whh0 = (const float*)d_in[2];
    const float* bih0 = (const float*)d_in[3];
    const float* bhh0 = (const float*)d_in[4];
    const float* Wih1 = (const float*)d_in[5];
    const float* Whh1 = (const float*)d_in[6];
    const float* bih1 = (const float*)d_in[7];
    const float* bhh1 = (const float*)d_in[8];
    const float* Wh1  = (const float*)d_in[9];
    const float* bh1  = (const float*)d_in[10];
    const float* Wh2  = (const float*)d_in[11];
    const float* bh2  = (const float*)d_in[12];
    float* out = (float*)d_out;

    const int B = out_size;              // 2048
    const int grid = B / B_TILE;         // 512 blocks, 2 per CU

    lstm2_kernel<<<grid, 256, 0, stream>>>(x, Wih0, Whh0, bih0, bhh0,
                                           Wih1, Whh1, bih1, bhh1,
                                           Wh1, bh1, Wh2, bh2, out);
}

// Round 3
// 49926.242 us; speedup vs baseline: 1.2620x; 1.2620x over previous
//
#include <hip/hip_runtime.h>

#define T_LEN 512
#define HID   64
#define NG    256   // 4*HID gate rows
#define B_TILE 4

typedef float f4 __attribute__((ext_vector_type(4)));

__device__ __forceinline__ float sigm(float x)  { return 1.0f / (1.0f + __expf(-x)); }
__device__ __forceinline__ float tanh_f(float x){ float e = __expf(2.0f * x); return 1.0f - 2.0f / (e + 1.0f); }

#define REP16(M) M(0) M(1) M(2) M(3) M(4) M(5) M(6) M(7) \
                 M(8) M(9) M(10) M(11) M(12) M(13) M(14) M(15)

__global__ __launch_bounds__(256, 2)
void lstm2_kernel(const float* __restrict__ x,
                  const float* __restrict__ Wih0, const float* __restrict__ Whh0,
                  const float* __restrict__ bih0, const float* __restrict__ bhh0,
                  const float* __restrict__ Wih1, const float* __restrict__ Whh1,
                  const float* __restrict__ bih1, const float* __restrict__ bhh1,
                  const float* __restrict__ Wh1,  const float* __restrict__ bh1,
                  const float* __restrict__ Wh2,  const float* __restrict__ bh2,
                  float* __restrict__ out)
{
    // [h][b] layout: one ds_read_b128 broadcast serves all 4 batch lanes
    __shared__ __align__(16) float xs[T_LEN][4][B_TILE];   // 32 KB, [t][f][b]
    __shared__ __align__(16) float h1s[HID][B_TILE];       // 1 KB
    __shared__ __align__(16) float h2s[HID][B_TILE];       // 1 KB
    __shared__ __align__(16) float g0s[NG][B_TILE];        // 4 KB
    __shared__ __align__(16) float g1s[NG][B_TILE];        // 4 KB
    __shared__ __align__(16) float hds[32][B_TILE];

    const int tid = threadIdx.x;
    const int b0  = blockIdx.x * B_TILE;
    const int g   = tid;            // gate row owned by this thread
    const int j   = tid & 63;       // hidden channel for update phase
    const int bb  = tid >> 6;       // batch lane for update phase
    const int wv  = tid >> 6;       // wave id -> gate type (0:i 1:f 2:g 3:o)

    // ---- per-thread weights: 48 NAMED f4 registers (no arrays -> no scratch) ----
    const f4 wih0r = *(const f4*)(Wih0 + g * 4);
    const f4* p0 = (const f4*)(Whh0 + g * HID);
    const f4* p1 = (const f4*)(Wih1 + g * HID);
    const f4* p2 = (const f4*)(Whh1 + g * HID);
#define D0(k) f4 w0_##k = p0[k];
#define D1(k) f4 w1_##k = p1[k];
#define D2(k) f4 w2_##k = p2[k];
    REP16(D0)
    REP16(D1)
    REP16(D2)

    const float bias0 = bih0[g] + bhh0[g];
    const float bias1 = bih1[g] + bhh1[g];

    // ---- stage x slice: x[b0+bb][t][f] -> xs[t][f][bb] ----
    {
        const f4* xg = (const f4*)(x + (size_t)b0 * T_LEN * 4);
        for (int i = tid; i < B_TILE * T_LEN; i += 256) {
            const int xb = i >> 9;          // /T_LEN
            const int t  = i & (T_LEN - 1);
            f4 v = xg[i];
#pragma unroll
            for (int f = 0; f < 4; ++f) xs[t][f][xb] = v[f];
        }
    }
    ((float*)h1s)[tid] = 0.0f;   // HID*B_TILE == 256 == blockDim
    ((float*)h2s)[tid] = 0.0f;
    float c1 = 0.0f, c2 = 0.0f;

    __syncthreads();

    const f4* h1v = (const f4*)h1s;   // h1v[h] = h1s[h][0..3] (broadcast read)
    const f4* h2v = (const f4*)h2s;

    for (int t = 0; t < T_LEN; ++t) {
        // ---- layer 0 matvec: gates0[b][g] ----
        {
            f4 acc = {bias0, bias0, bias0, bias0};
            {
                f4 xv0 = *(const f4*)&xs[t][0][0];
                f4 xv1 = *(const f4*)&xs[t][1][0];
                f4 xv2 = *(const f4*)&xs[t][2][0];
                f4 xv3 = *(const f4*)&xs[t][3][0];
                acc += xv0 * wih0r[0];
                acc += xv1 * wih0r[1];
                acc += xv2 * wih0r[2];
                acc += xv3 * wih0r[3];
            }
#define M0(k) { const f4 hv0 = h1v[4*(k)+0], hv1 = h1v[4*(k)+1], \
                         hv2 = h1v[4*(k)+2], hv3 = h1v[4*(k)+3]; \
                acc += hv0 * w0_##k[0]; acc += hv1 * w0_##k[1];  \
                acc += hv2 * w0_##k[2]; acc += hv3 * w0_##k[3]; }
            REP16(M0)
            f4 av;
            if (wv == 2) {
#pragma unroll
                for (int i = 0; i < 4; ++i) av[i] = tanh_f(acc[i]);
            } else {
#pragma unroll
                for (int i = 0; i < 4; ++i) av[i] = sigm(acc[i]);
            }
            *(f4*)&g0s[g][0] = av;
        }
        __syncthreads();
        // ---- layer 0 elementwise update ----
        {
            float ig = g0s[j][bb], fg = g0s[64 + j][bb], gg = g0s[128 + j][bb], og = g0s[192 + j][bb];
            c1 = fg * c1 + ig * gg;
            h1s[j][bb] = og * tanh_f(c1);
        }
        __syncthreads();
        // ---- layer 1 matvec: gates1[b][g] (inputs h1_t and h2_{t-1}) ----
        {
            f4 acc = {bias1, bias1, bias1, bias1};
#define M1(k) { const f4 hv0 = h1v[4*(k)+0], hv1 = h1v[4*(k)+1], \
                         hv2 = h1v[4*(k)+2], hv3 = h1v[4*(k)+3]; \
                acc += hv0 * w1_##k[0]; acc += hv1 * w1_##k[1];  \
                acc += hv2 * w1_##k[2]; acc += hv3 * w1_##k[3]; }
            REP16(M1)
#define M2(k) { const f4 hv0 = h2v[4*(k)+0], hv1 = h2v[4*(k)+1], \
                         hv2 = h2v[4*(k)+2], hv3 = h2v[4*(k)+3]; \
                acc += hv0 * w2_##k[0]; acc += hv1 * w2_##k[1];  \
                acc += hv2 * w2_##k[2]; acc += hv3 * w2_##k[3]; }
            REP16(M2)
            f4 av;
            if (wv == 2) {
#pragma unroll
                for (int i = 0; i < 4; ++i) av[i] = tanh_f(acc[i]);
            } else {
#pragma unroll
                for (int i = 0; i < 4; ++i) av[i] = sigm(acc[i]);
            }
            *(f4*)&g1s[g][0] = av;
        }
        __syncthreads();
        // ---- layer 1 elementwise update (no barrier needed before next MV0:
        // MV0 touches only xs/h1s/g0s, all disjoint from h2s/g1s) ----
        {
            float ig = g1s[j][bb], fg = g1s[64 + j][bb], gg = g1s[128 + j][bb], og = g1s[192 + j][bb];
            c2 = fg * c2 + ig * gg;
            h2s[j][bb] = og * tanh_f(c2);
        }
    }
    __syncthreads();

    // ---- head: Linear(64,32) + ReLU + Linear(32,1) ----
    if (tid < 128) {
        const int k = tid & 31, b = tid >> 5;
        float a = bh1[k];
#pragma unroll 8
        for (int jj = 0; jj < HID; ++jj) a += Wh1[k * HID + jj] * h2s[jj][b];
        hds[k][b] = fmaxf(a, 0.0f);
    }
    __syncthreads();
    if (tid < B_TILE) {
        float a = bh2[0];
#pragma unroll
        for (int k = 0; k < 32; ++k) a += Wh2[k] * hds[k][tid];
        out[b0 + tid] = a;
    }
}

extern "C" void kernel_launch(void* const* d_in, const int* in_sizes, int n_in,
                              void* d_out, int out_size, void* d_ws, size_t ws_size,
                              hipStream_t stream) {
    const float* x    = (const float*)d_in[0];
    const float* Wih0 = (const float*)d_in[1];
    const float* Whh0 = (const float*)d_in[2];
    const float* bih0 = (const float*)d_in[3];
    const float* bhh0 = (const float*)d_in[4];
    const float* Wih1 = (const float*)d_in[5];
    const float* Whh1 = (const float*)d_in[6];
    const float* bih1 = (const float*)d_in[7];
    const float* bhh1 = (const float*)d_in[8];
    const float* Wh1  = (const float*)d_in[9];
    const float* bh1  = (const float*)d_in[10];
    const float* Wh2  = (const float*)d_in[11];
    const float* bh2  = (const float*)d_in[12];
    float* out = (float*)d_out;

    const int B = out_size;              // 2048
    const int grid = B / B_TILE;         // 512 blocks, 2 per CU

    lstm2_kernel<<<grid, 256, 0, stream>>>(x, Wih0, Whh0, bih0, bhh0,
                                           Wih1, Whh1, bih1, bhh1,
                                           Wh1, bh1, Wh2, bh2, out);
}

// Round 8
// 27537.094 us; speedup vs baseline: 2.2881x; 1.8131x over previous
//
#include <hip/hip_runtime.h>

#define T_LEN 512
#define HID   64
#define NG    256   // 4*HID gate rows
#define B_TILE 4
#define NTHR  512

typedef float f4 __attribute__((ext_vector_type(4)));

__device__ __forceinline__ float sigm(float x)  { return 1.0f / (1.0f + __expf(-x)); }
__device__ __forceinline__ float tanh_f(float x){ float e = __expf(2.0f * x); return 1.0f - 2.0f / (e + 1.0f); }

#define REP8(M) M(0) M(1) M(2) M(3) M(4) M(5) M(6) M(7)

// Lane-pair row split: lanes l and l^32 each own half (32 weights) of gate row
// g = wave*32 + (lane&31); halves combine via one shfl_xor(32) — no barrier.
// Per-thread weight regs: 3 * 8 f4 = 96 VGPRs -> whole kernel ~125, fits the
// 128-cap the allocator insists on (rounds 1/3 both spilled at 192+).
__global__ __attribute__((amdgpu_flat_work_group_size(NTHR, NTHR), amdgpu_waves_per_eu(2)))
void lstm2_kernel(const float* __restrict__ x,
                  const float* __restrict__ Wih0, const float* __restrict__ Whh0,
                  const float* __restrict__ bih0, const float* __restrict__ bhh0,
                  const float* __restrict__ Wih1, const float* __restrict__ Whh1,
                  const float* __restrict__ bih1, const float* __restrict__ bhh1,
                  const float* __restrict__ Wh1,  const float* __restrict__ bh1,
                  const float* __restrict__ Wh2,  const float* __restrict__ bh2,
                  float* __restrict__ out)
{
    // [h][b] layout: one ds_read_b128 broadcast serves all 4 batch lanes
    __shared__ __align__(16) float xs[T_LEN][4][B_TILE];   // 32 KB, [t][f][b]
    __shared__ __align__(16) float h1s[HID][B_TILE];       // 1 KB
    __shared__ __align__(16) float h2s[HID][B_TILE];       // 1 KB
    __shared__ __align__(16) float g0s[NG][B_TILE];        // 4 KB
    __shared__ __align__(16) float g1s[NG][B_TILE];        // 4 KB
    __shared__ __align__(16) float hds[32][B_TILE];

    const int tid   = threadIdx.x;
    const int wave  = tid >> 6;
    const int lane  = tid & 63;
    const int p     = lane >> 5;        // half-row index (0: h[0:32), 1: h[32:64))
    const int g     = wave * 32 + (lane & 31);   // gate row 0..255
    const int gtype = wave >> 1;        // 0:i 1:f 2:g(tanh) 3:o  (wave-uniform)
    const int b0    = blockIdx.x * B_TILE;
    const int j     = tid & 63;         // update-phase hidden channel
    const int bb    = (tid >> 6) & 3;   // update-phase batch lane (tid<256 only)

    // ---- per-thread HALF-row weights: 24 named f4 regs (96 VGPRs) ----
    const f4* q0 = (const f4*)(Whh0 + g * HID + p * 32);
    const f4* q1 = (const f4*)(Wih1 + g * HID + p * 32);
    const f4* q2 = (const f4*)(Whh1 + g * HID + p * 32);
#define D0(k) f4 a0_##k = q0[k];
#define D1(k) f4 a1_##k = q1[k];
#define D2(k) f4 a2_##k = q2[k];
    REP8(D0)
    REP8(D1)
    REP8(D2)

    f4 wih0r = *(const f4*)(Wih0 + g * 4);
    if (p) wih0r = (f4){0.f, 0.f, 0.f, 0.f};           // x-part counted once
    const float b0eff = p ? 0.0f : (bih0[g] + bhh0[g]); // bias counted once
    const float b1eff = p ? 0.0f : (bih1[g] + bhh1[g]);

    // ---- stage x slice: x[b0+xb][t][f] -> xs[t][f][xb] ----
    {
        const f4* xg = (const f4*)(x + (size_t)b0 * T_LEN * 4);
        for (int i = tid; i < B_TILE * T_LEN; i += NTHR) {
            const int xb = i >> 9;          // /T_LEN
            const int t  = i & (T_LEN - 1);
            f4 v = xg[i];
#pragma unroll
            for (int f = 0; f < 4; ++f) xs[t][f][xb] = v[f];
        }
    }
    if (tid < 256) {                       // HID*B_TILE == 256
        ((float*)h1s)[tid] = 0.0f;
        ((float*)h2s)[tid] = 0.0f;
    }
    float c1 = 0.0f, c2 = 0.0f;

    __syncthreads();

    // broadcast f4 pointers into this thread's half of h
    const f4* h1p = ((const f4*)h1s) + p * 32;   // h1p[i] = h1s[p*32+i][0..3]
    const f4* h2p = ((const f4*)h2s) + p * 32;

    for (int t = 0; t < T_LEN; ++t) {
        // ---- layer 0 half-matvec + lane-pair combine ----
        {
            f4 acc = {b0eff, b0eff, b0eff, b0eff};
            {
                f4 xv0 = *(const f4*)&xs[t][0][0];
                f4 xv1 = *(const f4*)&xs[t][1][0];
                f4 xv2 = *(const f4*)&xs[t][2][0];
                f4 xv3 = *(const f4*)&xs[t][3][0];
                acc += xv0 * wih0r[0];
                acc += xv1 * wih0r[1];
                acc += xv2 * wih0r[2];
                acc += xv3 * wih0r[3];
            }
#define M0(k) { const f4 hv0 = h1p[4*(k)+0], hv1 = h1p[4*(k)+1], \
                         hv2 = h1p[4*(k)+2], hv3 = h1p[4*(k)+3]; \
                acc += hv0 * a0_##k[0]; acc += hv1 * a0_##k[1];  \
                acc += hv2 * a0_##k[2]; acc += hv3 * a0_##k[3]; }
            REP8(M0)
#pragma unroll
            for (int c = 0; c < 4; ++c) acc[c] += __shfl_xor(acc[c], 32);
            f4 av;
            if (gtype == 2) {
#pragma unroll
                for (int i = 0; i < 4; ++i) av[i] = tanh_f(acc[i]);
            } else {
#pragma unroll
                for (int i = 0; i < 4; ++i) av[i] = sigm(acc[i]);
            }
            if (p == 0) *(f4*)&g0s[g][0] = av;
        }
        __syncthreads();
        // ---- layer 0 elementwise update (waves 0-3) ----
        if (tid < 256) {
            float ig = g0s[j][bb], fg = g0s[64 + j][bb], gg = g0s[128 + j][bb], og = g0s[192 + j][bb];
            c1 = fg * c1 + ig * gg;
            h1s[j][bb] = og * tanh_f(c1);
        }
        __syncthreads();
        // ---- layer 1 half-matvec (h1_t and h2_{t-1}) + combine ----
        {
            f4 acc = {b1eff, b1eff, b1eff, b1eff};
#define M1(k) { const f4 hv0 = h1p[4*(k)+0], hv1 = h1p[4*(k)+1], \
                         hv2 = h1p[4*(k)+2], hv3 = h1p[4*(k)+3]; \
                acc += hv0 * a1_##k[0]; acc += hv1 * a1_##k[1];  \
                acc += hv2 * a1_##k[2]; acc += hv3 * a1_##k[3]; }
            REP8(M1)
#define M2(k) { const f4 hv0 = h2p[4*(k)+0], hv1 = h2p[4*(k)+1], \
                         hv2 = h2p[4*(k)+2], hv3 = h2p[4*(k)+3]; \
                acc += hv0 * a2_##k[0]; acc += hv1 * a2_##k[1];  \
                acc += hv2 * a2_##k[2]; acc += hv3 * a2_##k[3]; }
            REP8(M2)
#pragma unroll
            for (int c = 0; c < 4; ++c) acc[c] += __shfl_xor(acc[c], 32);
            f4 av;
            if (gtype == 2) {
#pragma unroll
                for (int i = 0; i < 4; ++i) av[i] = tanh_f(acc[i]);
            } else {
#pragma unroll
                for (int i = 0; i < 4; ++i) av[i] = sigm(acc[i]);
            }
            if (p == 0) *(f4*)&g1s[g][0] = av;
        }
        __syncthreads();
        // ---- layer 1 elementwise update (waves 0-3).  Next-iter MV0 touches
        // only xs/h1s/g0s, disjoint from h2s/g1s -> 3 barriers/step suffice ----
        if (tid < 256) {
            float ig = g1s[j][bb], fg = g1s[64 + j][bb], gg = g1s[128 + j][bb], og = g1s[192 + j][bb];
            c2 = fg * c2 + ig * gg;
            h2s[j][bb] = og * tanh_f(c2);
        }
    }
    __syncthreads();

    // ---- head: Linear(64,32) + ReLU + Linear(32,1) ----
    if (tid < 128) {
        const int k = tid & 31, b = tid >> 5;
        float a = bh1[k];
#pragma unroll 8
        for (int jj = 0; jj < HID; ++jj) a += Wh1[k * HID + jj] * h2s[jj][b];
        hds[k][b] = fmaxf(a, 0.0f);
    }
    __syncthreads();
    if (tid < B_TILE) {
        float a = bh2[0];
#pragma unroll
        for (int k = 0; k < 32; ++k) a += Wh2[k] * hds[k][tid];
        out[b0 + tid] = a;
    }
}

extern "C" void kernel_launch(void* const* d_in, const int* in_sizes, int n_in,
                              void* d_out, int out_size, void* d_ws, size_t ws_size,
                              hipStream_t stream) {
    const float* x    = (const float*)d_in[0];
    const float* Wih0 = (const float*)d_in[1];
    const float* Whh0 = (const float*)d_in[2];
    const float* bih0 = (const float*)d_in[3];
    const float* bhh0 = (const float*)d_in[4];
    const float* Wih1 = (const float*)d_in[5];
    const float* Whh1 = (const float*)d_in[6];
    const float* bih1 = (const float*)d_in[7];
    const float* bhh1 = (const float*)d_in[8];
    const float* Wh1  = (const float*)d_in[9];
    const float* bh1  = (const float*)d_in[10];
    const float* Wh2  = (const float*)d_in[11];
    const float* bh2  = (const float*)d_in[12];
    float* out = (float*)d_out;

    const int B = out_size;              // 2048
    const int grid = B / B_TILE;         // 512 blocks

    lstm2_kernel<<<grid, NTHR, 0, stream>>>(x, Wih0, Whh0, bih0, bhh0,
                                            Wih1, Whh1, bih1, bhh1,
                                            Wh1, bh1, Wh2, bh2, out);
}

// Round 9
// 11268.951 us; speedup vs baseline: 5.5912x; 2.4436x over previous
//
#include <hip/hip_runtime.h>

#define T_LEN  512
#define TCHUNK 128
#define HID    64
#define NG     256   // 4*HID gate rows
#define B_TILE 8
#define NTHR   1024

typedef float f4 __attribute__((ext_vector_type(4)));
typedef float f2 __attribute__((ext_vector_type(2)));

__device__ __forceinline__ float sigm(float x)  { return 1.0f / (1.0f + __expf(-x)); }
__device__ __forceinline__ float tanh_f(float x){ float e = __expf(2.0f * x); return 1.0f - 2.0f / (e + 1.0f); }

// Quarter-row split: 4 lanes (q=0..3, lanes r, r+16, r+32, r+48 of one wave)
// each own 16 of the 64 weights of gate row g = wave*16 + r.  Combine via
// shfl_xor(16)+shfl_xor(32).  Per-thread weights: 3*4 f4 = 48 VGPRs; whole
// kernel ~110 VGPRs -> fits the hard 128 cap with NO spill (rounds 1/3/8 all
// spilled: VGPR pinned at 128, FETCH 57-85 GB of scratch re-reads).
// h-state layout [r][q][b]: at unroll step r the 4 q-groups read 4 distinct
// bank-quads (word addr (r*4+q)*8) -> conflict-free broadcast ds_read_b128.
__global__ __launch_bounds__(NTHR)
void lstm2_kernel(const float* __restrict__ x,
                  const float* __restrict__ Wih0, const float* __restrict__ Whh0,
                  const float* __restrict__ bih0, const float* __restrict__ bhh0,
                  const float* __restrict__ Wih1, const float* __restrict__ Whh1,
                  const float* __restrict__ bih1, const float* __restrict__ bhh1,
                  const float* __restrict__ Wh1,  const float* __restrict__ bh1,
                  const float* __restrict__ Wh2,  const float* __restrict__ bh2,
                  float* __restrict__ out)
{
    __shared__ __align__(16) float xs[TCHUNK][4][B_TILE];    // 16 KB [t][f][b]
    __shared__ __align__(16) float h1s[16][4][B_TILE];       // 2 KB  [r][q][b]
    __shared__ __align__(16) float h2s[16][4][B_TILE];       // 2 KB
    __shared__ __align__(16) float g0s[NG][B_TILE];          // 8 KB
    __shared__ __align__(16) float g1s[NG][B_TILE];          // 8 KB
    __shared__ __align__(16) float hds[32][B_TILE];          // 1 KB

    const int tid   = threadIdx.x;
    const int wave  = tid >> 6;          // 0..15
    const int lane  = tid & 63;
    const int q     = (lane >> 4) & 3;   // quarter index
    const int r     = lane & 15;
    const int g     = wave * 16 + r;     // gate row 0..255
    const int gtype = wave >> 2;         // 0:i 1:f 2:g(tanh) 3:o (wave-uniform)
    const int b0    = blockIdx.x * B_TILE;

    // ---- per-thread QUARTER-row weights: 12 named f4 regs (48 VGPRs) ----
    const f4* q0p = (const f4*)(Whh0 + g * HID + q * 16);
    const f4* q1p = (const f4*)(Wih1 + g * HID + q * 16);
    const f4* q2p = (const f4*)(Whh1 + g * HID + q * 16);
    const f4 w0_0 = q0p[0], w0_1 = q0p[1], w0_2 = q0p[2], w0_3 = q0p[3];
    const f4 w1_0 = q1p[0], w1_1 = q1p[1], w1_2 = q1p[2], w1_3 = q1p[3];
    const f4 w2_0 = q2p[0], w2_1 = q2p[1], w2_2 = q2p[2], w2_3 = q2p[3];

    f4 wih0r = *(const f4*)(Wih0 + g * 4);
    if (q) wih0r = (f4){0.f, 0.f, 0.f, 0.f};              // x-part counted once
    const float b0eff = q ? 0.0f : (bih0[g] + bhh0[g]);    // bias counted once
    const float b1eff = q ? 0.0f : (bih1[g] + bhh1[g]);

    // ---- update-phase mapping (tid<512): bb fast -> conflict-free g reads ----
    const int ubb = tid & 7;
    const int uj  = (tid >> 3) & 63;
    float* h1w = &h1s[uj & 15][(uj >> 4) & 3][ubb];   // physical row of logical uj
    float* h2w = &h2s[uj & 15][(uj >> 4) & 3][ubb];

    if (tid < 512) { *h1w = 0.0f; *h2w = 0.0f; }       // (uj,ubb) covers all 512 cells
    float c1 = 0.0f, c2 = 0.0f;

    const float* h1b = &h1s[0][q][0];   // stride 32 floats per r-step
    const float* h2b = &h2s[0][q][0];

#define MV4(hb, base, W) { \
    const f4 aa0 = *(const f4*)((hb) + ((base)+0)*32); const f4 bb0v = *(const f4*)((hb) + ((base)+0)*32 + 4); \
    const f4 aa1 = *(const f4*)((hb) + ((base)+1)*32); const f4 bb1v = *(const f4*)((hb) + ((base)+1)*32 + 4); \
    const f4 aa2 = *(const f4*)((hb) + ((base)+2)*32); const f4 bb2v = *(const f4*)((hb) + ((base)+2)*32 + 4); \
    const f4 aa3 = *(const f4*)((hb) + ((base)+3)*32); const f4 bb3v = *(const f4*)((hb) + ((base)+3)*32 + 4); \
    accA += aa0*(W)[0]; accB += bb0v*(W)[0]; \
    accA += aa1*(W)[1]; accB += bb1v*(W)[1]; \
    accA += aa2*(W)[2]; accB += bb2v*(W)[2]; \
    accA += aa3*(W)[3]; accB += bb3v*(W)[3]; }

#define COMBINE() { \
    accA[0] += __shfl_xor(accA[0],16); accA[1] += __shfl_xor(accA[1],16); \
    accA[2] += __shfl_xor(accA[2],16); accA[3] += __shfl_xor(accA[3],16); \
    accB[0] += __shfl_xor(accB[0],16); accB[1] += __shfl_xor(accB[1],16); \
    accB[2] += __shfl_xor(accB[2],16); accB[3] += __shfl_xor(accB[3],16); \
    accA[0] += __shfl_xor(accA[0],32); accA[1] += __shfl_xor(accA[1],32); \
    accA[2] += __shfl_xor(accA[2],32); accA[3] += __shfl_xor(accA[3],32); \
    accB[0] += __shfl_xor(accB[0],32); accB[1] += __shfl_xor(accB[1],32); \
    accB[2] += __shfl_xor(accB[2],32); accB[3] += __shfl_xor(accB[3],32); }

    for (int tc = 0; tc < T_LEN / TCHUNK; ++tc) {
        // ---- stage x chunk: 8b x 128t, one f4 per thread ----
        {
            const int xb = tid >> 7;
            const int tt = tid & 127;
            f4 v = *(const f4*)(x + (((size_t)(b0 + xb)) * T_LEN + (tc * TCHUNK + tt)) * 4);
            xs[tt][0][xb] = v[0]; xs[tt][1][xb] = v[1];
            xs[tt][2][xb] = v[2]; xs[tt][3][xb] = v[3];
        }
        __syncthreads();

        for (int tt = 0; tt < TCHUNK; ++tt) {
            // ================= layer 0 matvec =================
            {
                f4 accA = {b0eff, b0eff, b0eff, b0eff};
                f4 accB = accA;
                const float* xt = &xs[tt][0][0];
                accA += (*(const f4*)(xt + 0))  * wih0r[0]; accB += (*(const f4*)(xt + 4))  * wih0r[0];
                accA += (*(const f4*)(xt + 8))  * wih0r[1]; accB += (*(const f4*)(xt + 12)) * wih0r[1];
                accA += (*(const f4*)(xt + 16)) * wih0r[2]; accB += (*(const f4*)(xt + 20)) * wih0r[2];
                accA += (*(const f4*)(xt + 24)) * wih0r[3]; accB += (*(const f4*)(xt + 28)) * wih0r[3];
                MV4(h1b, 0, w0_0); MV4(h1b, 4, w0_1); MV4(h1b, 8, w0_2); MV4(h1b, 12, w0_3);
                COMBINE();
                // each q-lane activates 2 of the 8 batch values
                f4 src = (q & 2) ? accB : accA;
                float v0 = (q & 1) ? src[2] : src[0];
                float v1 = (q & 1) ? src[3] : src[1];
                if (gtype == 2) { v0 = tanh_f(v0); v1 = tanh_f(v1); }
                else            { v0 = sigm(v0);   v1 = sigm(v1);   }
                f2 wv = {v0, v1};
                *(f2*)&g0s[g][q * 2] = wv;
            }
            __syncthreads();
            // ---- layer 0 elementwise update ----
            if (tid < 512) {
                float ig = g0s[uj][ubb], fg = g0s[64 + uj][ubb];
                float gg = g0s[128 + uj][ubb], og = g0s[192 + uj][ubb];
                c1 = fg * c1 + ig * gg;
                *h1w = og * tanh_f(c1);
            }
            __syncthreads();
            // ================= layer 1 matvec =================
            {
                f4 accA = {b1eff, b1eff, b1eff, b1eff};
                f4 accB = accA;
                MV4(h1b, 0, w1_0); MV4(h1b, 4, w1_1); MV4(h1b, 8, w1_2); MV4(h1b, 12, w1_3);
                MV4(h2b, 0, w2_0); MV4(h2b, 4, w2_1); MV4(h2b, 8, w2_2); MV4(h2b, 12, w2_3);
                COMBINE();
                f4 src = (q & 2) ? accB : accA;
                float v0 = (q & 1) ? src[2] : src[0];
                float v1 = (q & 1) ? src[3] : src[1];
                if (gtype == 2) { v0 = tanh_f(v0); v1 = tanh_f(v1); }
                else            { v0 = sigm(v0);   v1 = sigm(v1);   }
                f2 wv = {v0, v1};
                *(f2*)&g1s[g][q * 2] = wv;
            }
            __syncthreads();
            // ---- layer 1 elementwise update (writes h2s/g1s only; next
            // L0-matvec touches xs/h1s/g0s -> disjoint, no 4th barrier) ----
            if (tid < 512) {
                float ig = g1s[uj][ubb], fg = g1s[64 + uj][ubb];
                float gg = g1s[128 + uj][ubb], og = g1s[192 + uj][ubb];
                c2 = fg * c2 + ig * gg;
                *h2w = og * tanh_f(c2);
            }
            __syncthreads();   // h2s visible before next L1 matvec / restage
        }
    }

    // ---- head: Linear(64,32) + ReLU + Linear(32,1) ----
    if (tid < 256) {
        const int k = tid & 31, b = tid >> 5;
        float a = bh1[k];
#pragma unroll 8
        for (int jj = 0; jj < HID; ++jj)
            a += Wh1[k * HID + jj] * h2s[jj & 15][(jj >> 4) & 3][b];
        hds[k][b] = fmaxf(a, 0.0f);
    }
    __syncthreads();
    if (tid < B_TILE) {
        float a = bh2[0];
#pragma unroll
        for (int k = 0; k < 32; ++k) a += Wh2[k] * hds[k][tid];
        out[b0 + tid] = a;
    }
#undef MV4
#undef COMBINE
}

extern "C" void kernel_launch(void* const* d_in, const int* in_sizes, int n_in,
                              void* d_out, int out_size, void* d_ws, size_t ws_size,
                              hipStream_t stream) {
    const float* x    = (const float*)d_in[0];
    const float* Wih0 = (const float*)d_in[1];
    const float* Whh0 = (const float*)d_in[2];
    const float* bih0 = (const float*)d_in[3];
    const float* bhh0 = (const float*)d_in[4];
    const float* Wih1 = (const float*)d_in[5];
    const float* Whh1 = (const float*)d_in[6];
    const float* bih1 = (const float*)d_in[7];
    const float* bhh1 = (const float*)d_in[8];
    const float* Wh1  = (const float*)d_in[9];
    const float* bh1  = (const float*)d_in[10];
    const float* Wh2  = (const float*)d_in[11];
    const float* bh2  = (const float*)d_in[12];
    float* out = (float*)d_out;

    const int B = out_size;              // 2048
    const int grid = B / B_TILE;         // 256 blocks = 1 per CU

    lstm2_kernel<<<grid, NTHR, 0, stream>>>(x, Wih0, Whh0, bih0, bhh0,
                                            Wih1, Whh1, bih1, bhh1,
                                            Wh1, bh1, Wh2, bh2, out);
}